// Round 4
// baseline (142.542 us; speedup 1.0000x reference)
//
#include <hip/hip_runtime.h>
#include <math.h>
#include <stdint.h>

typedef unsigned short u16;
typedef __bf16 bf16x8 __attribute__((ext_vector_type(8)));
typedef float f32x4 __attribute__((ext_vector_type(4)));
typedef u16 u16x8 __attribute__((ext_vector_type(8)));

constexpr int Bb = 2, Ss = 2048, Dd = 1024, Hh = 16, Hd = 64, Win = 256;
constexpr int Mtot = Bb * Ss;   // 4096
constexpr int NTK = 16;         // K / 64 k-tiles for the 8-phase GEMM

// ---------- helpers ----------
__device__ __forceinline__ u16 f2bf(float f) {
    uint32_t u = __float_as_uint(f);
    u += 0x7fff + ((u >> 16) & 1);   // RNE
    return (u16)(u >> 16);
}

__device__ __forceinline__ void gload16(const void* g, void* l) {
    __builtin_amdgcn_global_load_lds(
        (const __attribute__((address_space(1))) uint32_t*)g,
        (__attribute__((address_space(3))) uint32_t*)l, 16, 0, 0);
}

// ---------- fp32 -> bf16 convert (vectorized) ----------
__global__ void cvt4(const float* __restrict__ s, u16* __restrict__ d, int n4) {
    int i = blockIdx.x * blockDim.x + threadIdx.x;
    if (i >= n4) return;
    float4 v = reinterpret_cast<const float4*>(s)[i];
    ushort4 o;
    o.x = f2bf(v.x); o.y = f2bf(v.y); o.z = f2bf(v.z); o.w = f2bf(v.w);
    reinterpret_cast<ushort4*>(d)[i] = o;
}

// 4 weight matrices in one dispatch (blockIdx.y selects)
__global__ void cvt4w(const float* __restrict__ s0, const float* __restrict__ s1,
                      const float* __restrict__ s2, const float* __restrict__ s3,
                      u16* __restrict__ d0, u16* __restrict__ d1,
                      u16* __restrict__ d2, u16* __restrict__ d3, int n4) {
    const int wsel = blockIdx.y;
    const float* s = (wsel == 0) ? s0 : (wsel == 1) ? s1 : (wsel == 2) ? s2 : s3;
    u16* d = (wsel == 0) ? d0 : (wsel == 1) ? d1 : (wsel == 2) ? d2 : d3;
    int i = blockIdx.x * blockDim.x + threadIdx.x;
    if (i >= n4) return;
    float4 v = reinterpret_cast<const float4*>(s)[i];
    ushort4 o;
    o.x = f2bf(v.x); o.y = f2bf(v.y); o.z = f2bf(v.z); o.w = f2bf(v.w);
    reinterpret_cast<ushort4*>(d)[i] = o;
}

// ---------- RoPE tables: cos/sin[s][d], freq index = d mod 32 ----------
__global__ void rope_tables(float* __restrict__ ct, float* __restrict__ st) {
    int i = blockIdx.x * blockDim.x + threadIdx.x;   // over Ss*64
    if (i >= Ss * 64) return;
    int s = i >> 6, d = i & 63;
    float invf = powf(10000.0f, -(float)(d & 31) / 32.0f);
    float ang = (float)s * invf;
    ct[i] = cosf(ang);
    st[i] = sinf(ang);
}

// ================== 256x256 8-phase QKV GEMM (T1+T2+T3/T4+T5) ==================
// A [4096][1024] bf16; W* [1024][1024] bf16 (row = out-col, k contig).
// Grid: 192 blocks of 512 threads (8 waves, 2M x 4N). N=3072 folded (by>>2 picks
// Q/K/V). LDS: 2 buffers x (A 2 halves + B 2 halves) x 16 KB = 128 KiB.
// Per tile sigma (4 phases = quadrants (ah,bh) in order (0,0),(1,0),(0,1),(1,1)):
//   stage stream: A1(s+1)@p0, B1(s+1)@p1, B0(s+2)@p2, A0(s+2)@p3  (1 half/phase)
//   vmcnt(6) at p0 => all 4 halves of tile s landed (3 halves in flight).
//   Every stage target slot is dead >=2 barriers before issue (derivation in
//   round notes): B0/A0[cur] last read at p0, staged at p2/p3; A1/B1[nxt] last
//   read 1 tile earlier.
// Swizzle: LDS byte (r,g) holds global k-granule g^(r&7) (16B granules,
// involutive XOR; applied at stage-src and ds_read addr) -> frag reads <=2-way.
#define MFMA_QUAD(AH, BH)                                                      \
    __builtin_amdgcn_s_setprio(1);                                             \
    _Pragma("unroll")                                                          \
    for (int fm = 0; fm < 4; ++fm)                                             \
      _Pragma("unroll")                                                        \
      for (int fn = 0; fn < 2; ++fn) {                                         \
        acc[AH][BH][fm][fn] = __builtin_amdgcn_mfma_f32_16x16x32_bf16(         \
            aF[AH][fm][0], bF[fn][0], acc[AH][BH][fm][fn], 0, 0, 0);           \
        acc[AH][BH][fm][fn] = __builtin_amdgcn_mfma_f32_16x16x32_bf16(         \
            aF[AH][fm][1], bF[fn][1], acc[AH][BH][fm][fn], 0, 0, 0);           \
      }                                                                        \
    __builtin_amdgcn_s_setprio(0);

__global__ __launch_bounds__(512, 2) void gemm_qkv(
    const u16* __restrict__ A,
    const u16* __restrict__ W0, const u16* __restrict__ W1, const u16* __restrict__ W2,
    u16* __restrict__ Qo, u16* __restrict__ Ko, u16* __restrict__ Vo,
    const float* __restrict__ ct, const float* __restrict__ st)
{
    __shared__ u16 sA[2][2][128 * 64];
    __shared__ u16 sB[2][2][128 * 64];

    const int t = threadIdx.x;
    const int l = t & 63, w = t >> 6;
    const int wm = w >> 2, wn = w & 3;            // 2M x 4N wave grid
    const int lr = l & 15, hi = l >> 4;

    int wg = blockIdx.x;
    wg = (wg & 7) * 24 + (wg >> 3);               // XCD swizzle (192 = 8*24, bijective)
    const int bx = wg & 15, by = wg >> 4;         // 16 M-tiles x 12 N-tiles
    const int m0 = bx * 256;
    const int mat = by >> 2;                      // 0:Q 1:K 2:V
    const int n0g = (by & 3) * 256;               // col base within its 1024 matrix
    const u16* Wm = (mat == 0) ? W0 : (mat == 1) ? W1 : W2;
    u16* Cm = (mat == 0) ? Qo : (mat == 1) ? Ko : Vo;

    auto stageA = [&](int buf, int h, int kt) {
#pragma unroll
        for (int p = 0; p < 2; ++p) {
            int x = (p * 512 + t) * 16;           // linear byte in 16 KB half-tile
            int r = x >> 7, gg = ((x >> 4) & 7) ^ (r & 7);
            gload16(A + (size_t)(m0 + h * 128 + r) * 1024 + kt * 64 + gg * 8,
                    (char*)&sA[buf][h][0] + x);
        }
    };
    auto stageB = [&](int buf, int h, int kt) {
#pragma unroll
        for (int p = 0; p < 2; ++p) {
            int x = (p * 512 + t) * 16;
            int r = x >> 7, gg = ((x >> 4) & 7) ^ (r & 7);
            gload16(Wm + (size_t)(n0g + h * 128 + r) * 1024 + kt * 64 + gg * 8,
                    (char*)&sB[buf][h][0] + x);
        }
    };
    auto rdA = [&](int buf, int half, int fm, int ks) -> bf16x8 {
        int r = wm * 64 + fm * 16 + lr;
        int g = (ks * 4 + hi) ^ (r & 7);
        return *reinterpret_cast<const bf16x8*>((const char*)&sA[buf][half][0] + r * 128 + g * 16);
    };
    auto rdB = [&](int buf, int half, int fn, int ks) -> bf16x8 {
        int r = wn * 32 + fn * 16 + lr;
        int g = (ks * 4 + hi) ^ (r & 7);
        return *reinterpret_cast<const bf16x8*>((const char*)&sB[buf][half][0] + r * 128 + g * 16);
    };

    // prologue: queue order B0(0),A0(0),A1(0),B1(0),B0(1),A0(1)
    stageB(0, 0, 0); stageA(0, 0, 0); stageA(0, 1, 0); stageB(0, 1, 0);
    stageB(1, 0, 1); stageA(1, 0, 1);

    f32x4 acc[2][2][4][2] = {};
    bf16x8 aF[2][4][2], bF[2][2];

    for (int s = 0; s < NTK; ++s) {
        const int cur = s & 1, nxt = cur ^ 1;

        // ---- phase 0: quadrant (0,0) ----
        if (s + 1 < NTK) stageA(nxt, 1, s + 1);
        if (s == NTK - 1) { asm volatile("s_waitcnt vmcnt(0)" ::: "memory"); }
        else              { asm volatile("s_waitcnt vmcnt(6)" ::: "memory"); }
#pragma unroll
        for (int fm = 0; fm < 4; ++fm) {
            aF[0][fm][0] = rdA(cur, 0, fm, 0);
            aF[0][fm][1] = rdA(cur, 0, fm, 1);
        }
#pragma unroll
        for (int fn = 0; fn < 2; ++fn) {
            bF[fn][0] = rdB(cur, 0, fn, 0);
            bF[fn][1] = rdB(cur, 0, fn, 1);
        }
        __builtin_amdgcn_s_barrier();
        MFMA_QUAD(0, 0)
        __builtin_amdgcn_s_barrier();

        // ---- phase 1: quadrant (1,0) ----
        if (s + 1 < NTK) stageB(nxt, 1, s + 1);
#pragma unroll
        for (int fm = 0; fm < 4; ++fm) {
            aF[1][fm][0] = rdA(cur, 1, fm, 0);
            aF[1][fm][1] = rdA(cur, 1, fm, 1);
        }
        __builtin_amdgcn_s_barrier();
        MFMA_QUAD(1, 0)
        __builtin_amdgcn_s_barrier();

        // ---- phase 2: quadrant (0,1) ----
        if (s + 2 < NTK) stageB(cur, 0, s + 2);
#pragma unroll
        for (int fn = 0; fn < 2; ++fn) {
            bF[fn][0] = rdB(cur, 1, fn, 0);
            bF[fn][1] = rdB(cur, 1, fn, 1);
        }
        __builtin_amdgcn_s_barrier();
        MFMA_QUAD(0, 1)
        __builtin_amdgcn_s_barrier();

        // ---- phase 3: quadrant (1,1) ----
        if (s + 2 < NTK) stageA(cur, 0, s + 2);
        __builtin_amdgcn_s_barrier();
        MFMA_QUAD(1, 1)
        __builtin_amdgcn_s_barrier();
    }

    // ---- epilogue: RoPE (Q,K) + bf16 cast, write [bh][s][64] ----
    const bool dorope = (mat < 2);
#pragma unroll
    for (int ah = 0; ah < 2; ++ah) {
#pragma unroll
        for (int bh = 0; bh < 2; ++bh) {
#pragma unroll
            for (int fm = 0; fm < 4; ++fm) {
#pragma unroll
                for (int fn = 0; fn < 2; ++fn) {
#pragma unroll
                    for (int j = 0; j < 4; ++j) {
                        int row = m0 + ah * 128 + wm * 64 + fm * 16 + hi * 4 + j;
                        int cim = n0g + bh * 128 + wn * 32 + fn * 16 + lr;
                        float v = acc[ah][bh][fm][fn][j];
                        float vp = __shfl_xor(v, 1);   // col^1 lives in lane^1
                        int b = row >> 11, sIdx = row & 2047;
                        int h = cim >> 6, d = cim & 63;
                        float outv = v;
                        if (dorope) {
                            float c = ct[sIdx * 64 + d], sn = st[sIdx * 64 + d];
                            outv = (d & 1) ? (v * c + vp * sn) : (v * c - vp * sn);
                        }
                        Cm[(((size_t)(b * 16 + h)) * 2048 + sIdx) * 64 + d] = f2bf(outv);
                    }
                }
            }
        }
    }
}

// ---------- bf16 MFMA GEMM (m97-style), used for the Wo projection ----------
__global__ __launch_bounds__(256) void gemm_wo(
    const u16* __restrict__ A, const u16* __restrict__ Bw,
    float* __restrict__ C, int M, int N, int Kd)
{
    __shared__ u16 sA[128 * 32];
    __shared__ u16 sB[128 * 32];

    const int t = threadIdx.x, l = t & 63, w = t >> 6;
    const int wm = w >> 1, wn = w & 1;
    const int m0 = blockIdx.x * 128, n0 = blockIdx.y * 128;
    const int lr = l & 15, kg = l >> 4;

    f32x4 acc[4][4] = {};

    for (int k0 = 0; k0 < Kd; k0 += 32) {
        __syncthreads();
#pragma unroll
        for (int p = 0; p < 2; ++p) {
            int i = p * 256 + t;
            int r = i >> 2, c = (i & 3) * 8;
            gload16(A  + (size_t)(m0 + r) * Kd + k0 + c, &sA[i * 8]);
            gload16(Bw + (size_t)(n0 + r) * Kd + k0 + c, &sB[i * 8]);
        }
        __syncthreads();

        bf16x8 af[4], bfr[4];
#pragma unroll
        for (int im = 0; im < 4; ++im)
            af[im] = *reinterpret_cast<const bf16x8*>(&sA[(wm * 64 + im * 16 + lr) * 32 + kg * 8]);
#pragma unroll
        for (int in = 0; in < 4; ++in)
            bfr[in] = *reinterpret_cast<const bf16x8*>(&sB[(wn * 64 + in * 16 + lr) * 32 + kg * 8]);
#pragma unroll
        for (int im = 0; im < 4; ++im)
#pragma unroll
            for (int in = 0; in < 4; ++in)
                acc[im][in] = __builtin_amdgcn_mfma_f32_16x16x32_bf16(af[im], bfr[in], acc[im][in], 0, 0, 0);
    }

#pragma unroll
    for (int im = 0; im < 4; ++im)
#pragma unroll
        for (int in = 0; in < 4; ++in)
#pragma unroll
            for (int j = 0; j < 4; ++j) {
                int row = m0 + wm * 64 + im * 16 + kg * 4 + j;
                int col = n0 + wn * 64 + in * 16 + lr;
                C[(size_t)row * N + col] = acc[im][in][j];
            }
}

// ---------- MFMA flash attention, window=256 ----------
__global__ __launch_bounds__(256) void fattn(
    const u16* __restrict__ Qb, const u16* __restrict__ Kb,
    const u16* __restrict__ Vb, u16* __restrict__ O)
{
    __shared__ u16 sQ[64 * 64];
    __shared__ u16 sK[64 * 64];
    __shared__ u16 sVT[64 * 64];
    __shared__ u16 sP[4][16 * 64];

    const int t = threadIdx.x, l = t & 63, w = t >> 6;
    const int lo = l & 15, hi = l >> 4;
    const int qt = blockIdx.x, bh = blockIdx.y;
    const int q0 = qt * 64;

    const char* Qg = (const char*)(Qb + ((size_t)bh * Ss + q0) * 64);
#pragma unroll
    for (int p = 0; p < 2; ++p) {
        uint32_t x = (uint32_t)(w * 2 + p) * 1024 + l * 16;
        uint32_t sx = x ^ (((x >> 7) & 7) << 4);
        gload16(Qg + sx, (char*)sQ + x);
    }
    __syncthreads();

    bf16x8 qf[2];
#pragma unroll
    for (int ck = 0; ck < 2; ++ck) {
        uint32_t b = (uint32_t)(w * 16 + lo) * 128 + ck * 64 + hi * 16;
        b ^= ((lo & 7) << 4);
        qf[ck] = *reinterpret_cast<const bf16x8*>((const char*)sQ + b);
    }

    f32x4 o[4] = {};
    float mj[4], lj[4];
#pragma unroll
    for (int j = 0; j < 4; ++j) { mj[j] = -1e30f; lj[j] = 0.f; }

    const int jt0 = (qt >= 4) ? qt - 4 : 0;
    for (int jt = jt0; jt <= qt; ++jt) {
        __syncthreads();
        const char* Kg = (const char*)(Kb + ((size_t)bh * Ss + jt * 64) * 64);
#pragma unroll
        for (int p = 0; p < 2; ++p) {
            uint32_t x = (uint32_t)(w * 2 + p) * 1024 + l * 16;
            uint32_t sx = x ^ (((x >> 7) & 7) << 4);
            gload16(Kg + sx, (char*)sK + x);
        }
        const u16* Vg = Vb + ((size_t)bh * Ss + jt * 64) * 64;
#pragma unroll
        for (int p = 0; p < 2; ++p) {
            int c = p * 256 + t;
            int kr = c >> 3, dc = (c & 7) * 8;
            u16x8 vv = *reinterpret_cast<const u16x8*>(Vg + (size_t)kr * 64 + dc);
#pragma unroll
            for (int ii = 0; ii < 8; ++ii) {
                int d = dc + ii;
                uint32_t b = ((uint32_t)d * 128 + kr * 2) ^ (((uint32_t)(d & 7)) << 4);
                *(u16*)((char*)sVT + b) = vv[ii];
            }
        }
        __syncthreads();

        f32x4 s4[4] = {};
#pragma unroll
        for (int ck = 0; ck < 2; ++ck) {
#pragma unroll
            for (int nb = 0; nb < 4; ++nb) {
                uint32_t b = (uint32_t)(nb * 16 + lo) * 128 + ck * 64 + hi * 16;
                b ^= ((lo & 7) << 4);
                bf16x8 kf = *reinterpret_cast<const bf16x8*>((const char*)sK + b);
                s4[nb] = __builtin_amdgcn_mfma_f32_16x16x32_bf16(qf[ck], kf, s4[nb], 0, 0, 0);
            }
        }

        const int qbase = q0 + w * 16 + hi * 4;
#pragma unroll
        for (int nb = 0; nb < 4; ++nb) {
            int k = jt * 64 + nb * 16 + lo;
#pragma unroll
            for (int j = 0; j < 4; ++j) {
                int q = qbase + j;
                float v = s4[nb][j] * 0.125f;
                bool ok = (k <= q) && (q - k < Win);
                s4[nb][j] = ok ? v : -1e30f;
            }
        }

#pragma unroll
        for (int j = 0; j < 4; ++j) {
            float tm = fmaxf(fmaxf(s4[0][j], s4[1][j]), fmaxf(s4[2][j], s4[3][j]));
            tm = fmaxf(tm, __shfl_xor(tm, 1));
            tm = fmaxf(tm, __shfl_xor(tm, 2));
            tm = fmaxf(tm, __shfl_xor(tm, 4));
            tm = fmaxf(tm, __shfl_xor(tm, 8));
            float nm = fmaxf(fmaxf(mj[j], tm), -1e20f);
            float sc = __expf(mj[j] - nm);
            mj[j] = nm;
            lj[j] *= sc;
#pragma unroll
            for (int nb = 0; nb < 4; ++nb) o[nb][j] *= sc;
            float ps = 0.f;
#pragma unroll
            for (int nb = 0; nb < 4; ++nb) {
                float p = __expf(s4[nb][j] - nm);
                ps += p;
                s4[nb][j] = p;
            }
            lj[j] += ps;
        }

#pragma unroll
        for (int nb = 0; nb < 4; ++nb) {
#pragma unroll
            for (int j = 0; j < 4; ++j) {
                int r = hi * 4 + j;
                uint32_t b = ((uint32_t)r * 128 + (nb * 16 + lo) * 2) ^ (((uint32_t)(r & 7)) << 4);
                *(u16*)((char*)&sP[w][0] + b) = f2bf(s4[nb][j]);
            }
        }

#pragma unroll
        for (int ck = 0; ck < 2; ++ck) {
            uint32_t bp = ((uint32_t)lo * 128 + ck * 64 + hi * 16) ^ (((uint32_t)(lo & 7)) << 4);
            bf16x8 pa = *reinterpret_cast<const bf16x8*>((const char*)&sP[w][0] + bp);
#pragma unroll
            for (int nb = 0; nb < 4; ++nb) {
                uint32_t bb = ((uint32_t)(nb * 16 + lo) * 128 + ck * 64 + hi * 16) ^ (((uint32_t)(lo & 7)) << 4);
                bf16x8 vf = *reinterpret_cast<const bf16x8*>((const char*)sVT + bb);
                o[nb] = __builtin_amdgcn_mfma_f32_16x16x32_bf16(pa, vf, o[nb], 0, 0, 0);
            }
        }
    }

#pragma unroll
    for (int j = 0; j < 4; ++j) {
        float s = lj[j];
        s += __shfl_xor(s, 1);
        s += __shfl_xor(s, 2);
        s += __shfl_xor(s, 4);
        s += __shfl_xor(s, 8);
        lj[j] = 1.0f / s;
    }
    const int bq = bh >> 4, h = bh & 15;
#pragma unroll
    for (int nb = 0; nb < 4; ++nb) {
#pragma unroll
        for (int j = 0; j < 4; ++j) {
            int q = q0 + w * 16 + hi * 4 + j;
            int d = nb * 16 + lo;
            O[((size_t)(bq * Ss + q)) * Dd + h * 64 + d] = f2bf(o[nb][j] * lj[j]);
        }
    }
}

// ---------- launch ----------
extern "C" void kernel_launch(void* const* d_in, const int* in_sizes, int n_in,
                              void* d_out, int out_size, void* d_ws, size_t ws_size,
                              hipStream_t stream) {
    const float* x  = (const float*)d_in[0];
    const float* Wq = (const float*)d_in[1];
    const float* Wk = (const float*)d_in[2];
    const float* Wv = (const float*)d_in[3];
    const float* Wo = (const float*)d_in[4];
    float* out = (float*)d_out;

    char* ws = (char*)d_ws;
    size_t off = 0;
    auto carve = [&](size_t bytes) -> char* {
        char* p = ws + off;
        off += (bytes + 255) & ~(size_t)255;
        return p;
    };
    float* cosT = (float*)carve((size_t)Ss * 64 * 4);
    float* sinT = (float*)carve((size_t)Ss * 64 * 4);
    u16* xb  = (u16*)carve((size_t)Mtot * Dd * 2);
    u16* wqb = (u16*)carve((size_t)Dd * Dd * 2);
    u16* wkb = (u16*)carve((size_t)Dd * Dd * 2);
    u16* wvb = (u16*)carve((size_t)Dd * Dd * 2);
    u16* wob = (u16*)carve((size_t)Dd * Dd * 2);
    u16* Qbb = (u16*)carve((size_t)Mtot * Dd * 2);
    u16* Kbb = (u16*)carve((size_t)Mtot * Dd * 2);
    u16* Vbb = (u16*)carve((size_t)Mtot * Dd * 2);
    u16* attb = (u16*)carve((size_t)Mtot * Dd * 2);

    const int nx4 = Mtot * Dd / 4, nw4 = Dd * Dd / 4;
    cvt4<<<nx4 / 256, 256, 0, stream>>>(x, xb, nx4);
    cvt4w<<<dim3(nw4 / 256, 4), 256, 0, stream>>>(Wq, Wk, Wv, Wo, wqb, wkb, wvb, wob, nw4);
    rope_tables<<<(Ss * 64) / 256, 256, 0, stream>>>(cosT, sinT);

    gemm_qkv<<<dim3(192), 512, 0, stream>>>(xb, wqb, wkb, wvb, Qbb, Kbb, Vbb, cosT, sinT);

    fattn<<<dim3(Ss / 64, Bb * Hh), 256, 0, stream>>>(Qbb, Kbb, Vbb, attb);

    gemm_wo<<<dim3(Mtot / 128, Dd / 128), 256, 0, stream>>>(
        attb, wob, out, Mtot, Dd, Dd);
}

// Round 5
// 140.480 us; speedup vs baseline: 1.0147x; 1.0147x over previous
//
#include <hip/hip_runtime.h>
#include <math.h>
#include <stdint.h>

typedef unsigned short u16;
typedef __bf16 bf16x8 __attribute__((ext_vector_type(8)));
typedef float f32x4 __attribute__((ext_vector_type(4)));
typedef u16 u16x8 __attribute__((ext_vector_type(8)));

constexpr int Bb = 2, Ss = 2048, Dd = 1024, Hh = 16, Hd = 64, Win = 256;
constexpr int Mtot = Bb * Ss;   // 4096

// ---------- helpers ----------
__device__ __forceinline__ u16 f2bf(float f) {
    uint32_t u = __float_as_uint(f);
    u += 0x7fff + ((u >> 16) & 1);   // RNE
    return (u16)(u >> 16);
}

__device__ __forceinline__ void gload16(const void* g, void* l) {
    __builtin_amdgcn_global_load_lds(
        (const __attribute__((address_space(1))) uint32_t*)g,
        (__attribute__((address_space(3))) uint32_t*)l, 16, 0, 0);
}

// ---------- fp32 -> bf16 convert (vectorized) ----------
__global__ void cvt4(const float* __restrict__ s, u16* __restrict__ d, int n4) {
    int i = blockIdx.x * blockDim.x + threadIdx.x;
    if (i >= n4) return;
    float4 v = reinterpret_cast<const float4*>(s)[i];
    ushort4 o;
    o.x = f2bf(v.x); o.y = f2bf(v.y); o.z = f2bf(v.z); o.w = f2bf(v.w);
    reinterpret_cast<ushort4*>(d)[i] = o;
}

// 4 weight matrices in one dispatch (blockIdx.y selects)
__global__ void cvt4w(const float* __restrict__ s0, const float* __restrict__ s1,
                      const float* __restrict__ s2, const float* __restrict__ s3,
                      u16* __restrict__ d0, u16* __restrict__ d1,
                      u16* __restrict__ d2, u16* __restrict__ d3, int n4) {
    const int wsel = blockIdx.y;
    const float* s = (wsel == 0) ? s0 : (wsel == 1) ? s1 : (wsel == 2) ? s2 : s3;
    u16* d = (wsel == 0) ? d0 : (wsel == 1) ? d1 : (wsel == 2) ? d2 : d3;
    int i = blockIdx.x * blockDim.x + threadIdx.x;
    if (i >= n4) return;
    float4 v = reinterpret_cast<const float4*>(s)[i];
    ushort4 o;
    o.x = f2bf(v.x); o.y = f2bf(v.y); o.z = f2bf(v.z); o.w = f2bf(v.w);
    reinterpret_cast<ushort4*>(d)[i] = o;
}

// ---------- RoPE tables: cos/sin[s][d], freq index = d mod 32 ----------
__global__ void rope_tables(float* __restrict__ ct, float* __restrict__ st) {
    int i = blockIdx.x * blockDim.x + threadIdx.x;   // over Ss*64
    if (i >= Ss * 64) return;
    int s = i >> 6, d = i & 63;
    float invf = powf(10000.0f, -(float)(d & 31) / 32.0f);
    float ang = (float)s * invf;
    ct[i] = cosf(ang);
    st[i] = sinf(ang);
}

// ================== 256x256 8-phase QKV GEMM — STATIC buffers ==================
// A [4096][1024] bf16; W* [1024][1024] bf16. Grid 192 x 512thr (8 waves 2Mx4N).
// 8 distinct named LDS arrays (2 bufs x 2 halves x {A,B}) so every gload_lds /
// ds_read target is a compile-time-known object -> waitcnt pass can prove
// dis-aliasing; counted vmcnt pipeline survives (round-4 runtime-indexed
// version collapsed to vmcnt(0)-per-phase).
// Per tile s (buf c = s&1): 4 phases = C-quadrants (0,0),(1,0),(0,1),(1,1).
//   p0: rd A0,B0; stage A1(s+1)->nxt   p1: rd A1; stage B1(s+1)->nxt
//   p2: rd B1; stage B0(s+2)->cur      p3: stage A0(s+2)->cur; vmcnt(4)
// Each phase: reads/stages -> barrier -> lgkmcnt(0) -> setprio(1) 16 MFMA -> barrier.
// vmcnt(4): 12 loads outstanding at p3, retire 8 = tile s+1's 4 halves exactly.
// Swizzle (involutive, 16B granules): LDS (r,g) holds global granule g^(r&7).

#define PH_PRE                                                 \
    __builtin_amdgcn_s_barrier();                              \
    asm volatile("s_waitcnt lgkmcnt(0)" ::: "memory");         \
    __builtin_amdgcn_s_setprio(1);

#define VM4 asm volatile("s_waitcnt vmcnt(4)" ::: "memory");
#define VM0 asm volatile("s_waitcnt vmcnt(0)" ::: "memory");
#define VMNONE

#define STAGE_A(DST, H, KT)                                                   \
    { _Pragma("unroll") for (int p_ = 0; p_ < 2; ++p_) {                      \
        int x_ = (p_ * 512 + t) * 16;                                         \
        int r_ = x_ >> 7, g_ = ((x_ >> 4) & 7) ^ (r_ & 7);                    \
        gload16(A + (size_t)(m0 + (H) * 128 + r_) * 1024 + (KT) * 64 + g_ * 8,\
                (char*)(DST) + x_); } }

#define STAGE_B(DST, H, KT)                                                   \
    { _Pragma("unroll") for (int p_ = 0; p_ < 2; ++p_) {                      \
        int x_ = (p_ * 512 + t) * 16;                                         \
        int r_ = x_ >> 7, g_ = ((x_ >> 4) & 7) ^ (r_ & 7);                    \
        gload16(Wm + (size_t)(n0g + (H) * 128 + r_) * 1024 + (KT) * 64 + g_ * 8,\
                (char*)(DST) + x_); } }

#define RD_A(SRC, DST)                                                        \
    _Pragma("unroll") for (int fm_ = 0; fm_ < 4; ++fm_)                       \
    _Pragma("unroll") for (int ks_ = 0; ks_ < 2; ++ks_) {                     \
        int r_ = wm * 64 + fm_ * 16 + lr;                                     \
        int g_ = (ks_ * 4 + hi) ^ (r_ & 7);                                   \
        DST[fm_][ks_] = *reinterpret_cast<const bf16x8*>(                     \
            reinterpret_cast<const char*>(SRC) + r_ * 128 + g_ * 16);         \
    }

#define RD_B(SRC, DST)                                                        \
    _Pragma("unroll") for (int fn_ = 0; fn_ < 2; ++fn_)                       \
    _Pragma("unroll") for (int ks_ = 0; ks_ < 2; ++ks_) {                     \
        int r_ = wn * 32 + fn_ * 16 + lr;                                     \
        int g_ = (ks_ * 4 + hi) ^ (r_ & 7);                                   \
        DST[fn_][ks_] = *reinterpret_cast<const bf16x8*>(                     \
            reinterpret_cast<const char*>(SRC) + r_ * 128 + g_ * 16);         \
    }

#define QUAD(AH, BH, AFR, BFR)                                                \
    _Pragma("unroll") for (int fm_ = 0; fm_ < 4; ++fm_)                       \
    _Pragma("unroll") for (int fn_ = 0; fn_ < 2; ++fn_) {                     \
        acc[AH][BH][fm_][fn_] = __builtin_amdgcn_mfma_f32_16x16x32_bf16(      \
            AFR[fm_][0], BFR[fn_][0], acc[AH][BH][fm_][fn_], 0, 0, 0);        \
        acc[AH][BH][fm_][fn_] = __builtin_amdgcn_mfma_f32_16x16x32_bf16(      \
            AFR[fm_][1], BFR[fn_][1], acc[AH][BH][fm_][fn_], 0, 0, 0);        \
    }

#define TILE(SA0, SA1, SB0, SB1, NA1, NB1, KT, STG1, STG2, VMF)               \
    RD_A(SA0, aF0) RD_B(SB0, bF0)                                             \
    if (STG1) { STAGE_A(NA1, 1, (KT) + 1) }                                   \
    PH_PRE QUAD(0, 0, aF0, bF0)                                               \
    __builtin_amdgcn_s_setprio(0); __builtin_amdgcn_s_barrier();              \
    RD_A(SA1, aF1)                                                            \
    if (STG1) { STAGE_B(NB1, 1, (KT) + 1) }                                   \
    PH_PRE QUAD(1, 0, aF1, bF0)                                               \
    __builtin_amdgcn_s_setprio(0); __builtin_amdgcn_s_barrier();              \
    RD_B(SB1, bF1)                                                            \
    if (STG2) { STAGE_B(SB0, 0, (KT) + 2) }                                   \
    PH_PRE QUAD(0, 1, aF0, bF1)                                               \
    __builtin_amdgcn_s_setprio(0); __builtin_amdgcn_s_barrier();              \
    if (STG2) { STAGE_A(SA0, 0, (KT) + 2) }                                   \
    PH_PRE QUAD(1, 1, aF1, bF1)                                               \
    __builtin_amdgcn_s_setprio(0); VMF __builtin_amdgcn_s_barrier();

__global__ __launch_bounds__(512, 2) void gemm_qkv(
    const u16* __restrict__ A,
    const u16* __restrict__ W0, const u16* __restrict__ W1, const u16* __restrict__ W2,
    u16* __restrict__ Qo, u16* __restrict__ Ko, u16* __restrict__ Vo,
    const float* __restrict__ ct, const float* __restrict__ st)
{
    // 8 distinct LDS objects: [buf][half] for A and B, 16 KiB each = 128 KiB
    __shared__ u16 sA00[8192], sA01[8192], sA10[8192], sA11[8192];
    __shared__ u16 sB00[8192], sB01[8192], sB10[8192], sB11[8192];

    const int t = threadIdx.x;
    const int l = t & 63, w = t >> 6;
    const int wm = w >> 2, wn = w & 3;            // 2M x 4N wave grid
    const int lr = l & 15, hi = l >> 4;

    int wg = blockIdx.x;
    wg = (wg & 7) * 24 + (wg >> 3);               // XCD swizzle (192 = 8*24, bijective)
    const int bx = wg & 15, by = wg >> 4;         // 16 M-tiles x 12 N-tiles
    const int m0 = bx * 256;
    const int mat = by >> 2;                      // 0:Q 1:K 2:V
    const int n0g = (by & 3) * 256;               // col base within its 1024 matrix
    const u16* Wm = (mat == 0) ? W0 : (mat == 1) ? W1 : W2;
    u16* Cm = (mat == 0) ? Qo : (mat == 1) ? Ko : Vo;

    f32x4 acc[2][2][4][2] = {};
    bf16x8 aF0[4][2], aF1[4][2], bF0[2][2], bF1[2][2];

    // prologue: tile0 all 4 halves + tile1 B0,A0; then retire tile0 (vmcnt 4)
    STAGE_B(sB00, 0, 0) STAGE_A(sA00, 0, 0) STAGE_A(sA01, 1, 0) STAGE_B(sB01, 1, 0)
    STAGE_B(sB10, 0, 1) STAGE_A(sA10, 0, 1)
    VM4
    __builtin_amdgcn_s_barrier();

    for (int it = 0; it < 7; ++it) {
        const int kt = 2 * it;
        TILE(sA00, sA01, sB00, sB01, sA11, sB11, kt,     true, true, VM4)
        TILE(sA10, sA11, sB10, sB11, sA01, sB01, kt + 1, true, true, VM4)
    }
    // tail: tiles 14,15 (no stages past K, drain at 14)
    TILE(sA00, sA01, sB00, sB01, sA11, sB11, 14, true,  false, VM0)
    TILE(sA10, sA11, sB10, sB11, sA01, sB01, 15, false, false, VMNONE)

    // ---- epilogue: RoPE (Q,K) + bf16 cast, write [bh][s][64] ----
    const bool dorope = (mat < 2);
#pragma unroll
    for (int ah = 0; ah < 2; ++ah) {
#pragma unroll
        for (int bh = 0; bh < 2; ++bh) {
#pragma unroll
            for (int fm = 0; fm < 4; ++fm) {
#pragma unroll
                for (int fn = 0; fn < 2; ++fn) {
#pragma unroll
                    for (int j = 0; j < 4; ++j) {
                        int row = m0 + ah * 128 + wm * 64 + fm * 16 + hi * 4 + j;
                        int cim = n0g + bh * 128 + wn * 32 + fn * 16 + lr;
                        float v = acc[ah][bh][fm][fn][j];
                        float vp = __shfl_xor(v, 1);   // col^1 lives in lane^1
                        int b = row >> 11, sIdx = row & 2047;
                        int h = cim >> 6, d = cim & 63;
                        float outv = v;
                        if (dorope) {
                            float c = ct[sIdx * 64 + d], sn = st[sIdx * 64 + d];
                            outv = (d & 1) ? (v * c + vp * sn) : (v * c - vp * sn);
                        }
                        Cm[(((size_t)(b * 16 + h)) * 2048 + sIdx) * 64 + d] = f2bf(outv);
                    }
                }
            }
        }
    }
}

// ---------- bf16 MFMA GEMM (m97-style), used for the Wo projection ----------
__global__ __launch_bounds__(256) void gemm_wo(
    const u16* __restrict__ A, const u16* __restrict__ Bw,
    float* __restrict__ C, int M, int N, int Kd)
{
    __shared__ u16 sA[128 * 32];
    __shared__ u16 sB[128 * 32];

    const int t = threadIdx.x, l = t & 63, w = t >> 6;
    const int wm = w >> 1, wn = w & 1;
    const int m0 = blockIdx.x * 128, n0 = blockIdx.y * 128;
    const int lr = l & 15, kg = l >> 4;

    f32x4 acc[4][4] = {};

    for (int k0 = 0; k0 < Kd; k0 += 32) {
        __syncthreads();
#pragma unroll
        for (int p = 0; p < 2; ++p) {
            int i = p * 256 + t;
            int r = i >> 2, c = (i & 3) * 8;
            gload16(A  + (size_t)(m0 + r) * Kd + k0 + c, &sA[i * 8]);
            gload16(Bw + (size_t)(n0 + r) * Kd + k0 + c, &sB[i * 8]);
        }
        __syncthreads();

        bf16x8 af[4], bfr[4];
#pragma unroll
        for (int im = 0; im < 4; ++im)
            af[im] = *reinterpret_cast<const bf16x8*>(&sA[(wm * 64 + im * 16 + lr) * 32 + kg * 8]);
#pragma unroll
        for (int in = 0; in < 4; ++in)
            bfr[in] = *reinterpret_cast<const bf16x8*>(&sB[(wn * 64 + in * 16 + lr) * 32 + kg * 8]);
#pragma unroll
        for (int im = 0; im < 4; ++im)
#pragma unroll
            for (int in = 0; in < 4; ++in)
                acc[im][in] = __builtin_amdgcn_mfma_f32_16x16x32_bf16(af[im], bfr[in], acc[im][in], 0, 0, 0);
    }

#pragma unroll
    for (int im = 0; im < 4; ++im)
#pragma unroll
        for (int in = 0; in < 4; ++in)
#pragma unroll
            for (int j = 0; j < 4; ++j) {
                int row = m0 + wm * 64 + im * 16 + kg * 4 + j;
                int col = n0 + wn * 64 + in * 16 + lr;
                C[(size_t)row * N + col] = acc[im][in][j];
            }
}

// ---------- MFMA flash attention, window=256 ----------
__global__ __launch_bounds__(256) void fattn(
    const u16* __restrict__ Qb, const u16* __restrict__ Kb,
    const u16* __restrict__ Vb, u16* __restrict__ O)
{
    __shared__ u16 sQ[64 * 64];
    __shared__ u16 sK[64 * 64];
    __shared__ u16 sVT[64 * 64];
    __shared__ u16 sP[4][16 * 64];

    const int t = threadIdx.x, l = t & 63, w = t >> 6;
    const int lo = l & 15, hi = l >> 4;
    const int qt = blockIdx.x, bh = blockIdx.y;
    const int q0 = qt * 64;

    const char* Qg = (const char*)(Qb + ((size_t)bh * Ss + q0) * 64);
#pragma unroll
    for (int p = 0; p < 2; ++p) {
        uint32_t x = (uint32_t)(w * 2 + p) * 1024 + l * 16;
        uint32_t sx = x ^ (((x >> 7) & 7) << 4);
        gload16(Qg + sx, (char*)sQ + x);
    }
    __syncthreads();

    bf16x8 qf[2];
#pragma unroll
    for (int ck = 0; ck < 2; ++ck) {
        uint32_t b = (uint32_t)(w * 16 + lo) * 128 + ck * 64 + hi * 16;
        b ^= ((lo & 7) << 4);
        qf[ck] = *reinterpret_cast<const bf16x8*>((const char*)sQ + b);
    }

    f32x4 o[4] = {};
    float mj[4], lj[4];
#pragma unroll
    for (int j = 0; j < 4; ++j) { mj[j] = -1e30f; lj[j] = 0.f; }

    const int jt0 = (qt >= 4) ? qt - 4 : 0;
    for (int jt = jt0; jt <= qt; ++jt) {
        __syncthreads();
        const char* Kg = (const char*)(Kb + ((size_t)bh * Ss + jt * 64) * 64);
#pragma unroll
        for (int p = 0; p < 2; ++p) {
            uint32_t x = (uint32_t)(w * 2 + p) * 1024 + l * 16;
            uint32_t sx = x ^ (((x >> 7) & 7) << 4);
            gload16(Kg + sx, (char*)sK + x);
        }
        const u16* Vg = Vb + ((size_t)bh * Ss + jt * 64) * 64;
#pragma unroll
        for (int p = 0; p < 2; ++p) {
            int c = p * 256 + t;
            int kr = c >> 3, dc = (c & 7) * 8;
            u16x8 vv = *reinterpret_cast<const u16x8*>(Vg + (size_t)kr * 64 + dc);
#pragma unroll
            for (int ii = 0; ii < 8; ++ii) {
                int d = dc + ii;
                uint32_t b = ((uint32_t)d * 128 + kr * 2) ^ (((uint32_t)(d & 7)) << 4);
                *(u16*)((char*)sVT + b) = vv[ii];
            }
        }
        __syncthreads();

        f32x4 s4[4] = {};
#pragma unroll
        for (int ck = 0; ck < 2; ++ck) {
#pragma unroll
            for (int nb = 0; nb < 4; ++nb) {
                uint32_t b = (uint32_t)(nb * 16 + lo) * 128 + ck * 64 + hi * 16;
                b ^= ((lo & 7) << 4);
                bf16x8 kf = *reinterpret_cast<const bf16x8*>((const char*)sK + b);
                s4[nb] = __builtin_amdgcn_mfma_f32_16x16x32_bf16(qf[ck], kf, s4[nb], 0, 0, 0);
            }
        }

        const int qbase = q0 + w * 16 + hi * 4;
#pragma unroll
        for (int nb = 0; nb < 4; ++nb) {
            int k = jt * 64 + nb * 16 + lo;
#pragma unroll
            for (int j = 0; j < 4; ++j) {
                int q = qbase + j;
                float v = s4[nb][j] * 0.125f;
                bool ok = (k <= q) && (q - k < Win);
                s4[nb][j] = ok ? v : -1e30f;
            }
        }

#pragma unroll
        for (int j = 0; j < 4; ++j) {
            float tm = fmaxf(fmaxf(s4[0][j], s4[1][j]), fmaxf(s4[2][j], s4[3][j]));
            tm = fmaxf(tm, __shfl_xor(tm, 1));
            tm = fmaxf(tm, __shfl_xor(tm, 2));
            tm = fmaxf(tm, __shfl_xor(tm, 4));
            tm = fmaxf(tm, __shfl_xor(tm, 8));
            float nm = fmaxf(fmaxf(mj[j], tm), -1e20f);
            float sc = __expf(mj[j] - nm);
            mj[j] = nm;
            lj[j] *= sc;
#pragma unroll
            for (int nb = 0; nb < 4; ++nb) o[nb][j] *= sc;
            float ps = 0.f;
#pragma unroll
            for (int nb = 0; nb < 4; ++nb) {
                float p = __expf(s4[nb][j] - nm);
                ps += p;
                s4[nb][j] = p;
            }
            lj[j] += ps;
        }

#pragma unroll
        for (int nb = 0; nb < 4; ++nb) {
#pragma unroll
            for (int j = 0; j < 4; ++j) {
                int r = hi * 4 + j;
                uint32_t b = ((uint32_t)r * 128 + (nb * 16 + lo) * 2) ^ (((uint32_t)(r & 7)) << 4);
                *(u16*)((char*)&sP[w][0] + b) = f2bf(s4[nb][j]);
            }
        }

#pragma unroll
        for (int ck = 0; ck < 2; ++ck) {
            uint32_t bp = ((uint32_t)lo * 128 + ck * 64 + hi * 16) ^ (((uint32_t)(lo & 7)) << 4);
            bf16x8 pa = *reinterpret_cast<const bf16x8*>((const char*)&sP[w][0] + bp);
#pragma unroll
            for (int nb = 0; nb < 4; ++nb) {
                uint32_t bb = ((uint32_t)(nb * 16 + lo) * 128 + ck * 64 + hi * 16) ^ (((uint32_t)(lo & 7)) << 4);
                bf16x8 vf = *reinterpret_cast<const bf16x8*>((const char*)sVT + bb);
                o[nb] = __builtin_amdgcn_mfma_f32_16x16x32_bf16(pa, vf, o[nb], 0, 0, 0);
            }
        }
    }

#pragma unroll
    for (int j = 0; j < 4; ++j) {
        float s = lj[j];
        s += __shfl_xor(s, 1);
        s += __shfl_xor(s, 2);
        s += __shfl_xor(s, 4);
        s += __shfl_xor(s, 8);
        lj[j] = 1.0f / s;
    }
    const int bq = bh >> 4, h = bh & 15;
#pragma unroll
    for (int nb = 0; nb < 4; ++nb) {
#pragma unroll
        for (int j = 0; j < 4; ++j) {
            int q = q0 + w * 16 + hi * 4 + j;
            int d = nb * 16 + lo;
            O[((size_t)(bq * Ss + q)) * Dd + h * 64 + d] = f2bf(o[nb][j] * lj[j]);
        }
    }
}

// ---------- launch ----------
extern "C" void kernel_launch(void* const* d_in, const int* in_sizes, int n_in,
                              void* d_out, int out_size, void* d_ws, size_t ws_size,
                              hipStream_t stream) {
    const float* x  = (const float*)d_in[0];
    const float* Wq = (const float*)d_in[1];
    const float* Wk = (const float*)d_in[2];
    const float* Wv = (const float*)d_in[3];
    const float* Wo = (const float*)d_in[4];
    float* out = (float*)d_out;

    char* ws = (char*)d_ws;
    size_t off = 0;
    auto carve = [&](size_t bytes) -> char* {
        char* p = ws + off;
        off += (bytes + 255) & ~(size_t)255;
        return p;
    };
    float* cosT = (float*)carve((size_t)Ss * 64 * 4);
    float* sinT = (float*)carve((size_t)Ss * 64 * 4);
    u16* xb  = (u16*)carve((size_t)Mtot * Dd * 2);
    u16* wqb = (u16*)carve((size_t)Dd * Dd * 2);
    u16* wkb = (u16*)carve((size_t)Dd * Dd * 2);
    u16* wvb = (u16*)carve((size_t)Dd * Dd * 2);
    u16* wob = (u16*)carve((size_t)Dd * Dd * 2);
    u16* Qbb = (u16*)carve((size_t)Mtot * Dd * 2);
    u16* Kbb = (u16*)carve((size_t)Mtot * Dd * 2);
    u16* Vbb = (u16*)carve((size_t)Mtot * Dd * 2);
    u16* attb = (u16*)carve((size_t)Mtot * Dd * 2);

    const int nx4 = Mtot * Dd / 4, nw4 = Dd * Dd / 4;
    cvt4<<<nx4 / 256, 256, 0, stream>>>(x, xb, nx4);
    cvt4w<<<dim3(nw4 / 256, 4), 256, 0, stream>>>(Wq, Wk, Wv, Wo, wqb, wkb, wvb, wob, nw4);
    rope_tables<<<(Ss * 64) / 256, 256, 0, stream>>>(cosT, sinT);

    gemm_qkv<<<dim3(192), 512, 0, stream>>>(xb, wqb, wkb, wvb, Qbb, Kbb, Vbb, cosT, sinT);

    fattn<<<dim3(Ss / 64, Bb * Hh), 256, 0, stream>>>(Qbb, Kbb, Vbb, attb);

    gemm_wo<<<dim3(Mtot / 128, Dd / 128), 256, 0, stream>>>(
        attb, wob, out, Mtot, Dd, Dd);
}